// Round 1
// baseline (887.665 us; speedup 1.0000x reference)
//
#include <hip/hip_runtime.h>
#include <stdint.h>

#define NCLASS 41
#define TLEN   1024
#define NBATCH 1024
// per-batch backpointer stride: (TLEN-1)*NCLASS = 41943, round to mult of 8
#define BP_STRIDE 41944

// ---------------------------------------------------------------------------
// Kernel A: Viterbi forward. One wave (64 threads) per batch element.
// Lane j owns state j (j < 41). Score broadcast via readlane (compile-time
// lane index after unroll). Backpointers -> uint8 in workspace.
// ---------------------------------------------------------------------------
__global__ __launch_bounds__(64) void crf_forward(
    const float* __restrict__ x,        // [B, T, C]
    const float* __restrict__ start_t,  // [C]
    const float* __restrict__ end_t,    // [C]
    const float* __restrict__ trans,    // [C, C]
    uint8_t* __restrict__ bp,           // [B, BP_STRIDE]
    int* __restrict__ out)              // [B, T]
{
    const int b = blockIdx.x;
    const int j = threadIdx.x;
    const bool act = (j < NCLASS);

    // Preload this lane's transition column: tc[i] = trans[i][j]
    float tc[NCLASS];
#pragma unroll
    for (int i = 0; i < NCLASS; ++i)
        tc[i] = act ? trans[i * NCLASS + j] : 0.0f;

    const float* xb = x + (size_t)b * TLEN * NCLASS;
    uint8_t* bpb = bp + (size_t)b * BP_STRIDE;

    float score = act ? (start_t[j] + xb[j]) : -3.0e38f;
    float emit_next = act ? xb[NCLASS + j] : 0.0f;  // t = 1 emission

    for (int t = 1; t < TLEN; ++t) {
        float emit = emit_next;
        if (t + 1 < TLEN)
            emit_next = act ? xb[(size_t)(t + 1) * NCLASS + j] : 0.0f;

        // Two independent max/argmax chains (first-index tie kept via strict >)
        float mA, mB;
        int aA, aB;
        {
            float s0 = __int_as_float(
                __builtin_amdgcn_readlane(__float_as_int(score), 0));
            mA = s0 + tc[0]; aA = 0;
        }
#pragma unroll
        for (int i = 1; i <= 20; ++i) {
            float s = __int_as_float(
                __builtin_amdgcn_readlane(__float_as_int(score), i));
            float v = s + tc[i];
            if (v > mA) { mA = v; aA = i; }
        }
        {
            float s21 = __int_as_float(
                __builtin_amdgcn_readlane(__float_as_int(score), 21));
            mB = s21 + tc[21]; aB = 21;
        }
#pragma unroll
        for (int i = 22; i < NCLASS; ++i) {
            float s = __int_as_float(
                __builtin_amdgcn_readlane(__float_as_int(score), i));
            float v = s + tc[i];
            if (v > mB) { mB = v; aB = i; }
        }
        float m = mA; int a = aA;
        if (mB > mA) { m = mB; a = aB; }  // all B-chain indices > A-chain: tie keeps A

        if (act) bpb[(size_t)(t - 1) * NCLASS + j] = (uint8_t)a;
        score = act ? (m + emit) : -3.0e38f;
    }

    // Final: add end transitions, argmax over lanes (first-index on tie)
    float fs = act ? (score + end_t[j]) : -3.0e38f;
    int idx = j;
#pragma unroll
    for (int off = 32; off >= 1; off >>= 1) {
        float ov = __shfl_xor(fs, off);
        int oi = __shfl_xor(idx, off);
        if (ov > fs || (ov == fs && oi < idx)) { fs = ov; idx = oi; }
    }
    if (j == 0) out[(size_t)b * TLEN + (TLEN - 1)] = idx;
}

// ---------------------------------------------------------------------------
// Kernel B: backtracking. One block (16 waves) per batch element.
// Whole backpointer history for the batch lives in LDS (~41 KB).
// Phase 1: wave w walks its 64-step chunk for ALL 41 entering-tag hypotheses
//          (lane = hypothesis) -> chunk boundary map.
// Stitch:  thread 0 composes the 16 boundary maps serially (16 steps).
// Phase 2: wave w replays its chunk with the true entering tag; lane l
//          captures the tag at its step; coalesced int32 store.
// ---------------------------------------------------------------------------
__global__ __launch_bounds__(1024) void crf_backtrack(
    const uint8_t* __restrict__ bp,
    int* __restrict__ out)
{
    __shared__ uint8_t bpl[BP_STRIDE];     // 41944 B
    __shared__ int maps[16][NCLASS];       // chunk boundary maps
    __shared__ int entry[16];              // true tag at each chunk end

    const int b = blockIdx.x;
    const int tid = threadIdx.x;
    const int w = tid >> 6;
    const int lane = tid & 63;

    // Cooperative load of this batch's backpointers into LDS (dword copies)
    {
        const uint32_t* src = (const uint32_t*)(bp + (size_t)b * BP_STRIDE);
        uint32_t* dst = (uint32_t*)bpl;
        for (int i = tid; i < BP_STRIDE / 4; i += 1024) dst[i] = src[i];
    }
    __syncthreads();

    const int cs = w * 64;
    const int ce = min(cs + 64, TLEN - 1);  // last chunk: 63 columns
    const int L = ce - cs;

    // Phase 1: hypothesis walk. bp column t lives at bpl[(t-1)*C + .]
    {
        int xx = (lane < NCLASS) ? lane : 0;
        for (int t = ce; t > cs; --t)
            xx = bpl[(t - 1) * NCLASS + xx];
        if (lane < NCLASS) maps[w][lane] = xx;
    }
    __syncthreads();

    // Stitch chunk boundaries (tag at time ce(w)) serially on one thread
    if (tid == 0) {
        int cur = out[(size_t)b * TLEN + (TLEN - 1)];  // tag @ T-1, from kernel A
        for (int ww = 15; ww >= 0; --ww) {
            entry[ww] = cur;
            cur = maps[ww][cur];
        }
    }
    __syncthreads();

    // Phase 2: replay with true entering tag; lane l captures step l's tag
    {
        int xx = entry[w];
        int cap = 0;
        for (int k = 0; k < L; ++k) {
            xx = bpl[(ce - 1 - k) * NCLASS + xx];
            if (k == lane) cap = xx;
        }
        if (lane < L) out[(size_t)b * TLEN + (ce - 1 - lane)] = cap;
    }
}

// ---------------------------------------------------------------------------
extern "C" void kernel_launch(void* const* d_in, const int* in_sizes, int n_in,
                              void* d_out, int out_size, void* d_ws, size_t ws_size,
                              hipStream_t stream) {
    const float* x       = (const float*)d_in[0];
    const float* start_t = (const float*)d_in[1];
    const float* end_t   = (const float*)d_in[2];
    const float* trans   = (const float*)d_in[3];
    int* out = (int*)d_out;
    uint8_t* bp = (uint8_t*)d_ws;  // needs NBATCH * BP_STRIDE = ~42.9 MB

    crf_forward<<<NBATCH, 64, 0, stream>>>(x, start_t, end_t, trans, bp, out);
    crf_backtrack<<<NBATCH, 1024, 0, stream>>>(bp, out);
}

// Round 2
// 861.993 us; speedup vs baseline: 1.0298x; 1.0298x over previous
//
#include <hip/hip_runtime.h>
#include <stdint.h>

#define NCLASS 41
#define TLEN   1024
#define NBATCH 1024
// per-batch backpointer stride: (TLEN-1)*NCLASS = 41943, round to mult of 8
#define BP_STRIDE 41944

// ---------------------------------------------------------------------------
// Kernel A: Viterbi forward. One wave (64 threads) per batch element.
// Lane j owns state j (j < 41). Score broadcast via readlane (compile-time
// lane index after unroll) -> SGPR, consumed directly by v_add.
// Max+argmax via index-tracking tournament tree: 40 independent matches,
// depth 6 -> issue-bound, not latency-bound.
// __launch_bounds__(64, 1): only 1 wave/SIMD ever resident (1024 waves on
// 1024 SIMDs), so let the allocator use a full register budget - the
// round-1 kernel spilled tc[41] to scratch at VGPR_Count=32.
// ---------------------------------------------------------------------------
__global__ __launch_bounds__(64, 1) void crf_forward(
    const float* __restrict__ x,        // [B, T, C]
    const float* __restrict__ start_t,  // [C]
    const float* __restrict__ end_t,    // [C]
    const float* __restrict__ trans,    // [C, C]
    uint8_t* __restrict__ bp,           // [B, BP_STRIDE]
    int* __restrict__ out)              // [B, T]
{
    const int b = blockIdx.x;
    const int j = threadIdx.x;
    const bool act = (j < NCLASS);
    const int jc = act ? j : (NCLASS - 1);  // clamped for always-valid loads

    // Preload this lane's transition column: tc[i] = trans[i][j]
    float tc[NCLASS];
#pragma unroll
    for (int i = 0; i < NCLASS; ++i)
        tc[i] = trans[i * NCLASS + jc];

    const float* xb = x + (size_t)b * TLEN * NCLASS;
    uint8_t* bpb = bp + (size_t)b * BP_STRIDE;

    float score = act ? (start_t[j] + xb[j]) : -3.0e38f;
    float emit_next = xb[NCLASS + jc];  // t = 1 emission (prefetched)

    for (int t = 1; t < TLEN; ++t) {
        float emit = emit_next;
        if (t + 1 < TLEN)
            emit_next = xb[(size_t)(t + 1) * NCLASS + jc];

        // v[i] = score[i] + trans[i][j]; score[i] broadcast via readlane
        float v[NCLASS];
#pragma unroll
        for (int i = 0; i < NCLASS; ++i) {
            float s = __int_as_float(
                __builtin_amdgcn_readlane(__float_as_int(score), i));
            v[i] = s + tc[i];
        }

        // Index-tracking tournament (first-index tie-break: >= keeps lower i;
        // each slot i's range is strictly before slot i+m's range).
        int id[NCLASS];
#pragma unroll
        for (int i = 0; i < NCLASS; ++i) id[i] = i;
#pragma unroll
        for (int m = 1; m < NCLASS; m <<= 1) {
#pragma unroll
            for (int i = 0; i + m < NCLASS; i += 2 * m) {
                bool c = v[i] >= v[i + m];
                v[i]  = c ? v[i]  : v[i + m];
                id[i] = c ? id[i] : id[i + m];
            }
        }

        if (act) bpb[(size_t)(t - 1) * NCLASS + j] = (uint8_t)id[0];
        score = act ? (v[0] + emit) : -3.0e38f;
    }

    // Final: add end transitions, argmax over lanes (first-index on tie)
    float fs = act ? (score + end_t[j]) : -3.0e38f;
    int idx = j;
#pragma unroll
    for (int off = 32; off >= 1; off >>= 1) {
        float ov = __shfl_xor(fs, off);
        int oi = __shfl_xor(idx, off);
        if (ov > fs || (ov == fs && oi < idx)) { fs = ov; idx = oi; }
    }
    if (j == 0) out[(size_t)b * TLEN + (TLEN - 1)] = idx;
}

// ---------------------------------------------------------------------------
// Kernel B: backtracking. One block (16 waves) per batch element.
// Whole backpointer history for the batch lives in LDS (~41 KB).
// Phase 1: wave w walks its 64-step chunk for ALL 41 entering-tag hypotheses
//          (lane = hypothesis) -> chunk boundary map.
// Stitch:  thread 0 composes the 16 boundary maps serially (16 steps).
// Phase 2: wave w replays its chunk with the true entering tag; lane l
//          captures the tag at its step; coalesced int32 store.
// ---------------------------------------------------------------------------
__global__ __launch_bounds__(1024) void crf_backtrack(
    const uint8_t* __restrict__ bp,
    int* __restrict__ out)
{
    __shared__ uint8_t bpl[BP_STRIDE];     // 41944 B
    __shared__ int maps[16][NCLASS];       // chunk boundary maps
    __shared__ int entry[16];              // true tag at each chunk end

    const int b = blockIdx.x;
    const int tid = threadIdx.x;
    const int w = tid >> 6;
    const int lane = tid & 63;

    // Cooperative load of this batch's backpointers into LDS (dword copies)
    {
        const uint32_t* src = (const uint32_t*)(bp + (size_t)b * BP_STRIDE);
        uint32_t* dst = (uint32_t*)bpl;
        for (int i = tid; i < BP_STRIDE / 4; i += 1024) dst[i] = src[i];
    }
    __syncthreads();

    const int cs = w * 64;
    const int ce = min(cs + 64, TLEN - 1);  // last chunk: 63 columns
    const int L = ce - cs;

    // Phase 1: hypothesis walk. bp column t lives at bpl[(t-1)*C + .]
    {
        int xx = (lane < NCLASS) ? lane : 0;
        for (int t = ce; t > cs; --t)
            xx = bpl[(t - 1) * NCLASS + xx];
        if (lane < NCLASS) maps[w][lane] = xx;
    }
    __syncthreads();

    // Stitch chunk boundaries (tag at time ce(w)) serially on one thread
    if (tid == 0) {
        int cur = out[(size_t)b * TLEN + (TLEN - 1)];  // tag @ T-1, from kernel A
        for (int ww = 15; ww >= 0; --ww) {
            entry[ww] = cur;
            cur = maps[ww][cur];
        }
    }
    __syncthreads();

    // Phase 2: replay with true entering tag; lane l captures step l's tag
    {
        int xx = entry[w];
        int cap = 0;
        for (int k = 0; k < L; ++k) {
            xx = bpl[(ce - 1 - k) * NCLASS + xx];
            if (k == lane) cap = xx;
        }
        if (lane < L) out[(size_t)b * TLEN + (ce - 1 - lane)] = cap;
    }
}

// ---------------------------------------------------------------------------
extern "C" void kernel_launch(void* const* d_in, const int* in_sizes, int n_in,
                              void* d_out, int out_size, void* d_ws, size_t ws_size,
                              hipStream_t stream) {
    const float* x       = (const float*)d_in[0];
    const float* start_t = (const float*)d_in[1];
    const float* end_t   = (const float*)d_in[2];
    const float* trans   = (const float*)d_in[3];
    int* out = (int*)d_out;
    uint8_t* bp = (uint8_t*)d_ws;  // needs NBATCH * BP_STRIDE = ~42.9 MB

    crf_forward<<<NBATCH, 64, 0, stream>>>(x, start_t, end_t, trans, bp, out);
    crf_backtrack<<<NBATCH, 1024, 0, stream>>>(bp, out);
}

// Round 3
// 254.796 us; speedup vs baseline: 3.4838x; 3.3831x over previous
//
#include <hip/hip_runtime.h>
#include <stdint.h>

#define NCLASS 41
#define TLEN   1024
#define NBATCH 1024
// per-batch backpointer stride: (TLEN-1)*NCLASS = 41943, round to mult of 8
#define BP_STRIDE 41944
#define NTRANS (NCLASS * NCLASS)

// Full-wave max + broadcast via DPP (row_shr 1/2/4/8, row_bcast 15/31).
// Lane 63 ends with the 64-lane max; readlane broadcasts it (SGPR).
__device__ __forceinline__ float wave_max_bcast(float x) {
    int xi = __float_as_int(x);
    int t;
    t = __builtin_amdgcn_update_dpp(xi, xi, 0x111, 0xf, 0xf, false);  // row_shr:1
    x = fmaxf(x, __int_as_float(t)); xi = __float_as_int(x);
    t = __builtin_amdgcn_update_dpp(xi, xi, 0x112, 0xf, 0xf, false);  // row_shr:2
    x = fmaxf(x, __int_as_float(t)); xi = __float_as_int(x);
    t = __builtin_amdgcn_update_dpp(xi, xi, 0x114, 0xf, 0xf, false);  // row_shr:4
    x = fmaxf(x, __int_as_float(t)); xi = __float_as_int(x);
    t = __builtin_amdgcn_update_dpp(xi, xi, 0x118, 0xf, 0xf, false);  // row_shr:8
    x = fmaxf(x, __int_as_float(t)); xi = __float_as_int(x);
    t = __builtin_amdgcn_update_dpp(xi, xi, 0x142, 0xf, 0xf, false);  // row_bcast:15
    x = fmaxf(x, __int_as_float(t)); xi = __float_as_int(x);
    t = __builtin_amdgcn_update_dpp(xi, xi, 0x143, 0xf, 0xf, false);  // row_bcast:31
    x = fmaxf(x, __int_as_float(t));
    return __int_as_float(__builtin_amdgcn_readlane(__float_as_int(x), 63));
}

// ---------------------------------------------------------------------------
// Kernel A: Viterbi forward with exact candidate pruning.
// One wave per batch element; lane j owns state j.
// Per step: M = wave_max(score); candidates = {i : score[i] >= M - D} where
// D = max(trans)-min(trans). Any i below that is STRICTLY below every
// column's max, so first-index argmax is preserved (iterate candidates in
// increasing i, strict > replace). E[|candidates|] ~ 1.3 for this data.
// Winner rows are fetched from LDS (uniform row index -> conflict-free).
// No per-lane arrays -> no scratch (rounds 1-2 died on scratch traffic).
// Emissions prefetched 4 steps ahead (step ~220cy < HBM latency ~900cy).
// ---------------------------------------------------------------------------
__global__ __launch_bounds__(64, 1) void crf_forward(
    const float* __restrict__ x,        // [B, T, C]
    const float* __restrict__ start_t,  // [C]
    const float* __restrict__ end_t,    // [C]
    const float* __restrict__ trans,    // [C, C]
    uint8_t* __restrict__ bp,           // [B, BP_STRIDE]
    int* __restrict__ out)              // [B, T]
{
    __shared__ float tl[NTRANS + 32];   // trans rows; +pad so row reads never OOB

    const int b = blockIdx.x;
    const int j = threadIdx.x;
    const bool act = (j < NCLASS);
    const int jc = act ? j : (NCLASS - 1);  // clamped lane for always-valid loads

    // Stage trans into LDS and compute D = max - min (exact, from data)
    float mx = -3.0e38f, mn = 3.0e38f;
    for (int k = j; k < NTRANS; k += 64) {
        float v = trans[k];
        tl[k] = v;
        mx = fmaxf(mx, v);
        mn = fminf(mn, v);
    }
    if (j >= NTRANS % 64) { /* nothing; all lanes covered loads above */ }
    __syncthreads();
    float Dmax = wave_max_bcast(mx);
    float Dmin = -wave_max_bcast(-mn);
    const float D = Dmax - Dmin;

    const float* xb = x + (size_t)b * TLEN * NCLASS;
    uint8_t* bpb = bp + (size_t)b * BP_STRIDE;

    float score = act ? (start_t[j] + xb[j]) : -3.0e38f;

    // One Viterbi step: consumes this step's emission, updates score, writes bp
    auto step = [&](float emit, int t) {
        float M = wave_max_bcast(score);
        float thr = M - D;
        unsigned long long m = __ballot(score >= thr);
        // >= 1 candidate always (the max itself). Peel the first.
        int ic = __ffsll(m) - 1;
        m &= m - 1;
        float sc = __int_as_float(
            __builtin_amdgcn_readlane(__float_as_int(score), ic));
        float best = sc + tl[ic * NCLASS + jc];
        int bidx = ic;
        while (m) {  // uniform (ballot result), scalar loop; rare
            ic = __ffsll(m) - 1;
            m &= m - 1;
            sc = __int_as_float(
                __builtin_amdgcn_readlane(__float_as_int(score), ic));
            float vc = sc + tl[ic * NCLASS + jc];
            if (vc > best) { best = vc; bidx = ic; }  // strict >: first index wins
        }
        if (act) bpb[(size_t)(t - 1) * NCLASS + j] = (uint8_t)bidx;
        score = act ? (best + emit) : -3.0e38f;
    };

    // Rolling 4-deep emission prefetch (rows t=1..4)
    float e0 = xb[1 * NCLASS + jc];
    float e1 = xb[2 * NCLASS + jc];
    float e2 = xb[3 * NCLASS + jc];
    float e3 = xb[4 * NCLASS + jc];

    int t0 = 1;
    for (; t0 + 3 <= TLEN - 4; t0 += 4) {  // t0 = 1..1017, steps 1..1020
        int r0 = t0 + 4, r1 = t0 + 5, r2 = t0 + 6, r3 = t0 + 7;
        r0 = r0 > TLEN - 1 ? TLEN - 1 : r0;
        r1 = r1 > TLEN - 1 ? TLEN - 1 : r1;
        r2 = r2 > TLEN - 1 ? TLEN - 1 : r2;
        r3 = r3 > TLEN - 1 ? TLEN - 1 : r3;
        step(e0, t0 + 0); e0 = xb[(size_t)r0 * NCLASS + jc];
        step(e1, t0 + 1); e1 = xb[(size_t)r1 * NCLASS + jc];
        step(e2, t0 + 2); e2 = xb[(size_t)r2 * NCLASS + jc];
        step(e3, t0 + 3); e3 = xb[(size_t)r3 * NCLASS + jc];
    }
    // Tail steps 1021..1023 (prefetched in the last group; e3 unused)
    step(e0, TLEN - 3);
    step(e1, TLEN - 2);
    step(e2, TLEN - 1);

    // Final: add end transitions, argmax over lanes (first-index on tie)
    float fs = act ? (score + end_t[j]) : -3.0e38f;
    int idx = j;
#pragma unroll
    for (int off = 32; off >= 1; off >>= 1) {
        float ov = __shfl_xor(fs, off);
        int oi = __shfl_xor(idx, off);
        if (ov > fs || (ov == fs && oi < idx)) { fs = ov; idx = oi; }
    }
    if (j == 0) out[(size_t)b * TLEN + (TLEN - 1)] = idx;
}

// ---------------------------------------------------------------------------
// Kernel B: backtracking (unchanged from round 2; measured cheap).
// ---------------------------------------------------------------------------
__global__ __launch_bounds__(1024) void crf_backtrack(
    const uint8_t* __restrict__ bp,
    int* __restrict__ out)
{
    __shared__ uint8_t bpl[BP_STRIDE];     // 41944 B
    __shared__ int maps[16][NCLASS];       // chunk boundary maps
    __shared__ int entry[16];              // true tag at each chunk end

    const int b = blockIdx.x;
    const int tid = threadIdx.x;
    const int w = tid >> 6;
    const int lane = tid & 63;

    {
        const uint32_t* src = (const uint32_t*)(bp + (size_t)b * BP_STRIDE);
        uint32_t* dst = (uint32_t*)bpl;
        for (int i = tid; i < BP_STRIDE / 4; i += 1024) dst[i] = src[i];
    }
    __syncthreads();

    const int cs = w * 64;
    const int ce = min(cs + 64, TLEN - 1);  // last chunk: 63 columns
    const int L = ce - cs;

    // Phase 1: hypothesis walk for all 41 entering tags (lane = hypothesis)
    {
        int xx = (lane < NCLASS) ? lane : 0;
        for (int t = ce; t > cs; --t)
            xx = bpl[(t - 1) * NCLASS + xx];
        if (lane < NCLASS) maps[w][lane] = xx;
    }
    __syncthreads();

    // Stitch chunk boundaries serially on one thread
    if (tid == 0) {
        int cur = out[(size_t)b * TLEN + (TLEN - 1)];  // tag @ T-1 from kernel A
        for (int ww = 15; ww >= 0; --ww) {
            entry[ww] = cur;
            cur = maps[ww][cur];
        }
    }
    __syncthreads();

    // Phase 2: replay with true entering tag; lane l captures step l's tag
    {
        int xx = entry[w];
        int cap = 0;
        for (int k = 0; k < L; ++k) {
            xx = bpl[(ce - 1 - k) * NCLASS + xx];
            if (k == lane) cap = xx;
        }
        if (lane < L) out[(size_t)b * TLEN + (ce - 1 - lane)] = cap;
    }
}

// ---------------------------------------------------------------------------
extern "C" void kernel_launch(void* const* d_in, const int* in_sizes, int n_in,
                              void* d_out, int out_size, void* d_ws, size_t ws_size,
                              hipStream_t stream) {
    const float* x       = (const float*)d_in[0];
    const float* start_t = (const float*)d_in[1];
    const float* end_t   = (const float*)d_in[2];
    const float* trans   = (const float*)d_in[3];
    int* out = (int*)d_out;
    uint8_t* bp = (uint8_t*)d_ws;  // needs NBATCH * BP_STRIDE = ~42.9 MB

    crf_forward<<<NBATCH, 64, 0, stream>>>(x, start_t, end_t, trans, bp, out);
    crf_backtrack<<<NBATCH, 1024, 0, stream>>>(bp, out);
}